// Round 1
// baseline (1797.267 us; speedup 1.0000x reference)
//
#include <hip/hip_runtime.h>
#include <hip/hip_bf16.h>

// Problem constants (from reference): B=4, T=512, H=2048, V=32000
#define B_ 4
#define T_ 512
#define H_ 2048
#define V_ 32000
#define M_ (B_ * T_)          // 2048 tokens
#define BETA_ 0.1f

// GEMM tiling: 128x128 block tile, BK=32, 256 threads (4 waves, each 64x64)
#define BM 128
#define BN 128
#define BK 32
#define NTILES (V_ / BN)      // 250 n-tiles
#define NP (NTILES * 2)       // 500 partials per row (per-64-col-wave granularity)

typedef __attribute__((ext_vector_type(8))) short short8;  // 8 bf16 = 4 VGPRs
typedef __attribute__((ext_vector_type(4))) float f32x4;   // MFMA accumulator

__device__ __forceinline__ void async_copy16(const void* g, void* l) {
  // global -> LDS direct copy, 16B per lane. LDS dest must be wave-uniform
  // base + lane*16 (it is: slot index = wave*64 + lane).
  __builtin_amdgcn_global_load_lds(
      (const __attribute__((address_space(1))) void*)g,
      (__attribute__((address_space(3))) void*)l, 16, 0, 0);
}

__device__ __forceinline__ unsigned short f2bf(float f) {
  // round-to-nearest-even fp32 -> bf16
  unsigned int u = __float_as_uint(f);
  u += 0x7fffu + ((u >> 16) & 1u);
  return (unsigned short)(u >> 16);
}

__global__ void cvt_bf16_kernel(const float* __restrict__ in,
                                unsigned short* __restrict__ out, int n4) {
  int i = blockIdx.x * blockDim.x + threadIdx.x;
  if (i < n4) {
    float4 v = ((const float4*)in)[i];
    ushort4 o;
    o.x = f2bf(v.x); o.y = f2bf(v.y); o.z = f2bf(v.z); o.w = f2bf(v.w);
    ((ushort4*)out)[i] = o;
  }
}

// Selected logit: exact fp32 dot(x[m,:], W[ids[m],:]). One wave per (model, token).
__global__ void sel_kernel(const float* __restrict__ x, const float* __restrict__ w,
                           const float* __restrict__ rx, const float* __restrict__ rw,
                           const int* __restrict__ ids, float* __restrict__ sel) {
  int gw = (blockIdx.x * 256 + threadIdx.x) >> 6;  // global wave id, 0..4095
  int l = threadIdx.x & 63;
  int md = gw >> 11;          // model: 0 = policy, 1 = ref
  int m = gw & (M_ - 1);      // token
  const float* xr = (md ? rx : x) + (size_t)m * H_;
  const float* wr = (md ? rw : w) + (size_t)ids[m] * H_;
  float s = 0.0f;
#pragma unroll
  for (int it = 0; it < H_ / 256; ++it) {   // 64 lanes * 4 floats = 256/iter
    int k = it * 256 + l * 4;
    float4 a = *(const float4*)(xr + k);
    float4 b = *(const float4*)(wr + k);
    s += a.x * b.x + a.y * b.y + a.z * b.z + a.w * b.w;
  }
#pragma unroll
  for (int off = 32; off; off >>= 1) s += __shfl_xor(s, off, 64);
  if (l == 0) sel[md * M_ + m] = s;
}

// Fused bf16 MFMA GEMM (logits = A * Bw^T, both K-major) + per-row online
// (max, sumexp) over this block's 64-column wave slab. m97-style structure:
// global_load_lds width-16 staging, 2-barrier K-loop, 16x16x32 bf16 MFMA,
// 4 waves each computing a 64x64 tile of the 128x128 block tile.
__global__ __launch_bounds__(256) void gemm_lse_kernel(
    const unsigned short* __restrict__ A,    // [M_][H_] bf16
    const unsigned short* __restrict__ Bw,   // [V_][H_] bf16
    float* __restrict__ pmax,                // [NP][M_]
    float* __restrict__ psum) {              // [NP][M_]
  __shared__ char smem[(BM + BN) * BK * 2];  // 16 KB: A tile then B tile
  char* As = smem;                 // slot s = kb*128 + row, 16 B each (8 bf16 of k)
  char* Bs = smem + BM * BK * 2;

  const int tid = threadIdx.x;
  const int w = tid >> 6, l = tid & 63;
  const int quad = l >> 4, lr = l & 15;
  const int m0 = blockIdx.x * BM, n0 = blockIdx.y * BN;
  const int wm = (w >> 1) * 64, wn = (w & 1) * 64;

  // Staging: 512 slots per matrix, 2 per thread. Slot s: kb = s>>7, row = s&127.
  const int s0 = tid, s1 = tid + 256;
  const unsigned short* gA0 = A + (size_t)(m0 + (s0 & 127)) * H_ + (s0 >> 7) * 8;
  const unsigned short* gA1 = A + (size_t)(m0 + (s1 & 127)) * H_ + (s1 >> 7) * 8;
  const unsigned short* gB0 = Bw + (size_t)(n0 + (s0 & 127)) * H_ + (s0 >> 7) * 8;
  const unsigned short* gB1 = Bw + (size_t)(n0 + (s1 & 127)) * H_ + (s1 >> 7) * 8;
  char* lA0 = As + s0 * 16; char* lA1 = As + s1 * 16;
  char* lB0 = Bs + s0 * 16; char* lB1 = Bs + s1 * 16;

  f32x4 acc[4][4] = {};

  // Fragment LDS addresses (A: m = wm + i*16 + lr, kb = quad; B: same with n)
  const char* aRd[4]; const char* bRd[4];
#pragma unroll
  for (int i = 0; i < 4; ++i) {
    aRd[i] = As + (quad * 128 + wm + i * 16 + lr) * 16;
    bRd[i] = Bs + (quad * 128 + wn + i * 16 + lr) * 16;
  }

  for (int kt = 0; kt < H_ / BK; ++kt) {
    async_copy16(gA0, lA0); async_copy16(gA1, lA1);
    async_copy16(gB0, lB0); async_copy16(gB1, lB1);
    gA0 += BK; gA1 += BK; gB0 += BK; gB1 += BK;
    __syncthreads();  // drains vmcnt -> LDS tile complete for all waves
    short8 af[4], bf[4];
#pragma unroll
    for (int i = 0; i < 4; ++i) af[i] = *(const short8*)aRd[i];
#pragma unroll
    for (int j = 0; j < 4; ++j) bf[j] = *(const short8*)bRd[j];
#pragma unroll
    for (int i = 0; i < 4; ++i)
#pragma unroll
      for (int j = 0; j < 4; ++j)
        acc[i][j] = __builtin_amdgcn_mfma_f32_16x16x32_bf16(af[i], bf[j], acc[i][j], 0, 0, 0);
    __syncthreads();  // protect LDS from next iteration's staging
  }

  // Epilogue: C/D layout col = lane&15 (n), row = quad*4 + reg (m within 16-tile).
  // For each of this wave's 64 rows: max + sumexp over its 64 columns.
  float* pm_out = pmax + (size_t)(blockIdx.y * 2 + (w & 1)) * M_ + m0;
  float* ps_out = psum + (size_t)(blockIdx.y * 2 + (w & 1)) * M_ + m0;
#pragma unroll
  for (int i = 0; i < 4; ++i) {
#pragma unroll
    for (int r = 0; r < 4; ++r) {
      float vmax = acc[i][0][r];
      vmax = fmaxf(vmax, acc[i][1][r]);
      vmax = fmaxf(vmax, acc[i][2][r]);
      vmax = fmaxf(vmax, acc[i][3][r]);
#pragma unroll
      for (int off = 8; off; off >>= 1) vmax = fmaxf(vmax, __shfl_xor(vmax, off, 64));
      float s = __expf(acc[i][0][r] - vmax) + __expf(acc[i][1][r] - vmax) +
                __expf(acc[i][2][r] - vmax) + __expf(acc[i][3][r] - vmax);
#pragma unroll
      for (int off = 8; off; off >>= 1) s += __shfl_xor(s, off, 64);
      if (lr == 0) {
        int mloc = wm + i * 16 + quad * 4 + r;
        pm_out[mloc] = vmax;
        ps_out[mloc] = s;
      }
    }
  }
}

// Merge NP partials per row -> lse; logp = sel - lse; GRPO loss terms; reduce.
__global__ void finalize_kernel(
    const float* __restrict__ pmaxP, const float* __restrict__ psumP,
    const float* __restrict__ pmaxR, const float* __restrict__ psumR,
    const float* __restrict__ sel, const float* __restrict__ adv,
    const int* __restrict__ mask, float* __restrict__ acc) {
  int m = blockIdx.x * blockDim.x + threadIdx.x;  // 2048 threads total
  float lp[2];
#pragma unroll
  for (int md = 0; md < 2; ++md) {
    const float* pm = md ? pmaxR : pmaxP;
    const float* ps = md ? psumR : psumP;
    float mx = -3.0e38f, s = 0.0f;
    for (int p = 0; p < NP; ++p) {
      float a = pm[(size_t)p * M_ + m];
      float b = ps[(size_t)p * M_ + m];
      float nm = fmaxf(mx, a);
      s = s * __expf(mx - nm) + b * __expf(a - nm);
      mx = nm;
    }
    lp[md] = sel[md * M_ + m] - (mx + __logf(s));
  }
  // coef1 = exp(lp - stopgrad(lp)) = 1 exactly; coef2 = clip(1,...) = 1
  // per_token_loss = -adv[b] + BETA * (exp(d) - d - 1), d = ref_lp - lp
  float d = lp[1] - lp[0];
  float kl = __expf(d) - d - 1.0f;
  float mk = (float)mask[m];
  float pt = (-adv[m >> 9] + BETA_ * kl) * mk;
#pragma unroll
  for (int off = 32; off; off >>= 1) {
    pt += __shfl_xor(pt, off, 64);
    mk += __shfl_xor(mk, off, 64);
  }
  __shared__ float sp[4], sm[4];
  int wv = threadIdx.x >> 6, l = threadIdx.x & 63;
  if (l == 0) { sp[wv] = pt; sm[wv] = mk; }
  __syncthreads();
  if (threadIdx.x == 0) {
    atomicAdd(&acc[0], sp[0] + sp[1] + sp[2] + sp[3]);
    atomicAdd(&acc[1], sm[0] + sm[1] + sm[2] + sm[3]);
  }
}

__global__ void finish_kernel(const float* __restrict__ acc, float* __restrict__ out) {
  out[0] = acc[0] / fmaxf(acc[1], 1.0f);
}

extern "C" void kernel_launch(void* const* d_in, const int* in_sizes, int n_in,
                              void* d_out, int out_size, void* d_ws, size_t ws_size,
                              hipStream_t stream) {
  const float* x    = (const float*)d_in[0];
  const float* lw   = (const float*)d_in[1];
  const float* rx   = (const float*)d_in[2];
  const float* rw   = (const float*)d_in[3];
  const float* adv  = (const float*)d_in[4];
  const int*   ids  = (const int*)d_in[5];
  const int*   mask = (const int*)d_in[6];
  float* out = (float*)d_out;

  // Workspace layout (~156 MB): acc | Wb (bf16, shared between models) |
  // xb (bf16, shared) | pmaxP | psumP | pmaxR | psumR | sel
  char* ws = (char*)d_ws;
  float* acc = (float*)ws;
  unsigned short* Wb = (unsigned short*)(ws + 256);
  unsigned short* xb = (unsigned short*)(ws + 256 + (size_t)V_ * H_ * 2);
  char* p0 = ws + 256 + (size_t)V_ * H_ * 2 + (size_t)M_ * H_ * 2;
  float* pmaxP = (float*)(p0);
  float* psumP = (float*)(p0 + 1 * (size_t)NP * M_ * 4);
  float* pmaxR = (float*)(p0 + 2 * (size_t)NP * M_ * 4);
  float* psumR = (float*)(p0 + 3 * (size_t)NP * M_ * 4);
  float* sel   = (float*)(p0 + 4 * (size_t)NP * M_ * 4);

  hipMemsetAsync(acc, 0, 2 * sizeof(float), stream);

  const int n4x = M_ * H_ / 4, n4w = V_ * H_ / 4;
  dim3 g(M_ / BM, NTILES);  // x fastest -> 16 m-blocks share each B n-tile in L2

  // Policy model
  cvt_bf16_kernel<<<(n4x + 255) / 256, 256, 0, stream>>>(x, xb, n4x);
  cvt_bf16_kernel<<<(n4w + 255) / 256, 256, 0, stream>>>(lw, Wb, n4w);
  sel_kernel<<<(2 * M_) / 4, 256, 0, stream>>>(x, lw, rx, rw, ids, sel);
  gemm_lse_kernel<<<g, 256, 0, stream>>>(xb, Wb, pmaxP, psumP);
  // Ref model (reuse bf16 buffers — stream-ordered, no overlap lost)
  cvt_bf16_kernel<<<(n4x + 255) / 256, 256, 0, stream>>>(rx, xb, n4x);
  cvt_bf16_kernel<<<(n4w + 255) / 256, 256, 0, stream>>>(rw, Wb, n4w);
  gemm_lse_kernel<<<g, 256, 0, stream>>>(xb, Wb, pmaxR, psumR);

  finalize_kernel<<<M_ / 256, 256, 0, stream>>>(pmaxP, psumP, pmaxR, psumR,
                                                sel, adv, mask, acc);
  finish_kernel<<<1, 1, 0, stream>>>(acc, out);
}

// Round 2
// 1665.013 us; speedup vs baseline: 1.0794x; 1.0794x over previous
//
#include <hip/hip_runtime.h>
#include <hip/hip_bf16.h>

// Problem constants (from reference): B=4, T=512, H=2048, V=32000
#define B_ 4
#define T_ 512
#define H_ 2048
#define V_ 32000
#define M_ (B_ * T_)          // 2048 tokens
#define BETA_ 0.1f

// GEMM tiling: 128x128 block tile, BK=32, 256 threads (4 waves, each 64x64)
#define BM 128
#define BN 128
#define BK 32
#define NTILES (V_ / BN)      // 250 n-tiles
#define NP (NTILES * 2)       // 500 partials per row (per-64-col-wave slab)
#define NPAD 512              // padded row length for [m][p] partial layout
#define GRID_LIN 4096         // 8 xcd * 32 grp * 16 mblk (some grp tails unused)

typedef __attribute__((ext_vector_type(8))) short short8;  // 8 bf16 = 4 VGPRs
typedef __attribute__((ext_vector_type(4))) float f32x4;   // MFMA accumulator

__device__ __forceinline__ void async_copy16(const void* g, void* l) {
  // global -> LDS direct copy, 16B per lane. LDS dest must be wave-uniform
  // base + lane*16 (it is: slot index = wave*64 + lane).
  __builtin_amdgcn_global_load_lds(
      (const __attribute__((address_space(1))) void*)g,
      (__attribute__((address_space(3))) void*)l, 16, 0, 0);
}

__device__ __forceinline__ unsigned short f2bf(float f) {
  unsigned int u = __float_as_uint(f);
  u += 0x7fffu + ((u >> 16) & 1u);
  return (unsigned short)(u >> 16);
}

__global__ void cvt_bf16_kernel(const float* __restrict__ in,
                                unsigned short* __restrict__ out, int n4) {
  int i = blockIdx.x * blockDim.x + threadIdx.x;
  if (i < n4) {
    float4 v = ((const float4*)in)[i];
    ushort4 o;
    o.x = f2bf(v.x); o.y = f2bf(v.y); o.z = f2bf(v.z); o.w = f2bf(v.w);
    ((ushort4*)out)[i] = o;
  }
}

// Selected logit: exact fp32 dot(x[m,:], W[ids[m],:]). One wave per (model, token).
__global__ void sel_kernel(const float* __restrict__ x, const float* __restrict__ w,
                           const float* __restrict__ rx, const float* __restrict__ rw,
                           const int* __restrict__ ids, float* __restrict__ sel) {
  int gw = (blockIdx.x * 256 + threadIdx.x) >> 6;  // global wave id, 0..4095
  int l = threadIdx.x & 63;
  int md = gw >> 11;          // model: 0 = policy, 1 = ref
  int m = gw & (M_ - 1);      // token
  const float* xr = (md ? rx : x) + (size_t)m * H_;
  const float* wr = (md ? rw : w) + (size_t)ids[m] * H_;
  float s = 0.0f;
#pragma unroll
  for (int it = 0; it < H_ / 256; ++it) {
    int k = it * 256 + l * 4;
    float4 a = *(const float4*)(xr + k);
    float4 b = *(const float4*)(wr + k);
    s += a.x * b.x + a.y * b.y + a.z * b.z + a.w * b.w;
  }
#pragma unroll
  for (int off = 32; off; off >>= 1) s += __shfl_xor(s, off, 64);
  if (l == 0) sel[md * M_ + m] = s;
}

// Fused bf16 MFMA GEMM (logits = A * Bw^T) + per-row online (max, sumexp) over
// this block's 64-column wave slab. XCD-aware 1-D grid decode: all 16 m-blocks
// of one n-tile share linear%8 (same XCD, per round-robin dispatch) and are
// dispatched consecutively -> the 524 KB B-tile is fetched into that XCD's L2
// once and staging loads become L2 hits (~200 cyc) instead of HBM (~900 cyc).
__global__ __launch_bounds__(256) void gemm_lse_kernel(
    const unsigned short* __restrict__ A,    // [M_][H_] bf16
    const unsigned short* __restrict__ Bw,   // [V_][H_] bf16
    float* __restrict__ pmax,                // [M_][NPAD]
    float* __restrict__ psum) {              // [M_][NPAD]
  const int linear = blockIdx.x;
  const int nt = (linear & 7) + 8 * (linear >> 7);   // n-tile, xcd-grouped
  if (nt >= NTILES) return;
  const int mb = (linear >> 3) & 15;                 // m-block

  __shared__ char smem[(BM + BN) * BK * 2];  // 16 KB: A tile then B tile
  char* As = smem;                 // slot s = kb*128 + row, 16 B each
  char* Bs = smem + BM * BK * 2;

  const int tid = threadIdx.x;
  const int w = tid >> 6, l = tid & 63;
  const int quad = l >> 4, lr = l & 15;
  const int m0 = mb * BM, n0 = nt * BN;
  const int wm = (w >> 1) * 64, wn = (w & 1) * 64;

  // Staging: 512 slots per matrix, 2 per thread. Slot s: kb = s>>7, row = s&127.
  const int s0 = tid, s1 = tid + 256;
  const unsigned short* gA0 = A + (size_t)(m0 + (s0 & 127)) * H_ + (s0 >> 7) * 8;
  const unsigned short* gA1 = A + (size_t)(m0 + (s1 & 127)) * H_ + (s1 >> 7) * 8;
  const unsigned short* gB0 = Bw + (size_t)(n0 + (s0 & 127)) * H_ + (s0 >> 7) * 8;
  const unsigned short* gB1 = Bw + (size_t)(n0 + (s1 & 127)) * H_ + (s1 >> 7) * 8;
  char* lA0 = As + s0 * 16; char* lA1 = As + s1 * 16;
  char* lB0 = Bs + s0 * 16; char* lB1 = Bs + s1 * 16;

  f32x4 acc[4][4] = {};

  const char* aRd[4]; const char* bRd[4];
#pragma unroll
  for (int i = 0; i < 4; ++i) {
    aRd[i] = As + (quad * 128 + wm + i * 16 + lr) * 16;
    bRd[i] = Bs + (quad * 128 + wn + i * 16 + lr) * 16;
  }

  for (int kt = 0; kt < H_ / BK; ++kt) {
    async_copy16(gA0, lA0); async_copy16(gA1, lA1);
    async_copy16(gB0, lB0); async_copy16(gB1, lB1);
    gA0 += BK; gA1 += BK; gB0 += BK; gB1 += BK;
    __syncthreads();
    short8 af[4], bf[4];
#pragma unroll
    for (int i = 0; i < 4; ++i) af[i] = *(const short8*)aRd[i];
#pragma unroll
    for (int j = 0; j < 4; ++j) bf[j] = *(const short8*)bRd[j];
#pragma unroll
    for (int i = 0; i < 4; ++i)
#pragma unroll
      for (int j = 0; j < 4; ++j)
        acc[i][j] = __builtin_amdgcn_mfma_f32_16x16x32_bf16(af[i], bf[j], acc[i][j], 0, 0, 0);
    __syncthreads();
  }

  // Epilogue: C/D layout col = lane&15 (n), row = quad*4 + reg.
  // Partials stored row-major [m][NPAD] so finalize reads coalesce.
  const int p_idx = nt * 2 + (w & 1);
#pragma unroll
  for (int i = 0; i < 4; ++i) {
#pragma unroll
    for (int r = 0; r < 4; ++r) {
      float vmax = fmaxf(fmaxf(acc[i][0][r], acc[i][1][r]),
                         fmaxf(acc[i][2][r], acc[i][3][r]));
#pragma unroll
      for (int off = 8; off; off >>= 1) vmax = fmaxf(vmax, __shfl_xor(vmax, off, 64));
      float s = __expf(acc[i][0][r] - vmax) + __expf(acc[i][1][r] - vmax) +
                __expf(acc[i][2][r] - vmax) + __expf(acc[i][3][r] - vmax);
#pragma unroll
      for (int off = 8; off; off >>= 1) s += __shfl_xor(s, off, 64);
      if (lr == 0) {
        int mg = m0 + wm + i * 16 + quad * 4 + r;
        pmax[(size_t)mg * NPAD + p_idx] = vmax;
        psum[(size_t)mg * NPAD + p_idx] = s;
      }
    }
  }
}

// One wave per (model, token): coalesced read of the token's 500 partials,
// online-merge per lane, shuffle-combine across lanes, write logp.
__global__ void lse_merge_kernel(
    const float* __restrict__ pmaxP, const float* __restrict__ psumP,
    const float* __restrict__ pmaxR, const float* __restrict__ psumR,
    const float* __restrict__ sel, float* __restrict__ lp) {
  int gw = (blockIdx.x * 256 + threadIdx.x) >> 6;  // 0..4095
  int l = threadIdx.x & 63;
  int md = gw >> 11, m = gw & (M_ - 1);
  const float* pm = (md ? pmaxR : pmaxP) + (size_t)m * NPAD;
  const float* ps = (md ? psumR : psumP) + (size_t)m * NPAD;
  float mx = -3.0e38f, s = 0.0f;
  for (int p = l; p < NP; p += 64) {
    float a = pm[p], b = ps[p];
    float nm = fmaxf(mx, a);
    s = s * __expf(mx - nm) + b * __expf(a - nm);
    mx = nm;
  }
#pragma unroll
  for (int off = 32; off; off >>= 1) {
    float omx = __shfl_xor(mx, off, 64);
    float os  = __shfl_xor(s, off, 64);
    float nm = fmaxf(mx, omx);
    s = s * __expf(mx - nm) + os * __expf(omx - nm);
    mx = nm;
  }
  if (l == 0) lp[md * M_ + m] = sel[md * M_ + m] - (mx + __logf(s));
}

// Single block: GRPO loss terms + masked mean. coef1=coef2=1 exactly
// (old_logps == stop_gradient(logps)), so loss = mean(-adv + BETA*kl).
__global__ void loss_kernel(const float* __restrict__ lp,
                            const float* __restrict__ adv,
                            const int* __restrict__ mask,
                            float* __restrict__ out) {
  __shared__ float sp[16], sm[16];
  int t = threadIdx.x;
  float pt = 0.0f, mk = 0.0f;
  for (int m = t; m < M_; m += 1024) {
    float d = lp[M_ + m] - lp[m];       // ref_logp - logp
    float kl = __expf(d) - d - 1.0f;
    float mkm = (float)mask[m];
    pt += (-adv[m >> 9] + BETA_ * kl) * mkm;
    mk += mkm;
  }
#pragma unroll
  for (int off = 32; off; off >>= 1) {
    pt += __shfl_xor(pt, off, 64);
    mk += __shfl_xor(mk, off, 64);
  }
  int wv = t >> 6, l = t & 63;
  if (l == 0) { sp[wv] = pt; sm[wv] = mk; }
  __syncthreads();
  if (t == 0) {
    float a = 0.0f, b = 0.0f;
#pragma unroll
    for (int i = 0; i < 16; ++i) { a += sp[i]; b += sm[i]; }
    out[0] = a / fmaxf(b, 1.0f);
  }
}

extern "C" void kernel_launch(void* const* d_in, const int* in_sizes, int n_in,
                              void* d_out, int out_size, void* d_ws, size_t ws_size,
                              hipStream_t stream) {
  const float* x    = (const float*)d_in[0];
  const float* lw   = (const float*)d_in[1];
  const float* rx   = (const float*)d_in[2];
  const float* rw   = (const float*)d_in[3];
  const float* adv  = (const float*)d_in[4];
  const int*   ids  = (const int*)d_in[5];
  const int*   mask = (const int*)d_in[6];
  float* out = (float*)d_out;

  // Workspace: Wb (bf16) | xb (bf16) | pmaxP|psumP|pmaxR|psumR ([M_][NPAD] f32)
  // | sel [2][M_] | lp [2][M_]   (~156.3 MB)
  char* ws = (char*)d_ws;
  unsigned short* Wb = (unsigned short*)ws;
  unsigned short* xb = (unsigned short*)(ws + (size_t)V_ * H_ * 2);
  char* p0 = ws + (size_t)V_ * H_ * 2 + (size_t)M_ * H_ * 2;
  const size_t PSZ = (size_t)M_ * NPAD * 4;
  float* pmaxP = (float*)(p0);
  float* psumP = (float*)(p0 + 1 * PSZ);
  float* pmaxR = (float*)(p0 + 2 * PSZ);
  float* psumR = (float*)(p0 + 3 * PSZ);
  float* sel   = (float*)(p0 + 4 * PSZ);
  float* lp    = (float*)(p0 + 4 * PSZ + 2 * M_ * 4);

  const int n4x = M_ * H_ / 4, n4w = V_ * H_ / 4;

  // Policy model
  cvt_bf16_kernel<<<(n4x + 255) / 256, 256, 0, stream>>>(x, xb, n4x);
  cvt_bf16_kernel<<<(n4w + 255) / 256, 256, 0, stream>>>(lw, Wb, n4w);
  sel_kernel<<<(2 * M_) / 4, 256, 0, stream>>>(x, lw, rx, rw, ids, sel);
  gemm_lse_kernel<<<GRID_LIN, 256, 0, stream>>>(xb, Wb, pmaxP, psumP);
  // Ref model (reuse bf16 buffers — stream-ordered)
  cvt_bf16_kernel<<<(n4x + 255) / 256, 256, 0, stream>>>(rx, xb, n4x);
  cvt_bf16_kernel<<<(n4w + 255) / 256, 256, 0, stream>>>(rw, Wb, n4w);
  gemm_lse_kernel<<<GRID_LIN, 256, 0, stream>>>(xb, Wb, pmaxR, psumR);

  lse_merge_kernel<<<(2 * M_) / 4, 256, 0, stream>>>(pmaxP, psumP, pmaxR, psumR,
                                                     sel, lp);
  loss_kernel<<<1, 1024, 0, stream>>>(lp, adv, mask, out);
}